// Round 11
// baseline (130.431 us; speedup 1.0000x reference)
//
#include <hip/hip_runtime.h>

#define B_  4
#define N_  4096
#define K_  32
#define C_  64
#define DH_ 128
#define PPW 4

typedef _Float16 half2v __attribute__((ext_vector_type(2)));
typedef _Float16 half8  __attribute__((ext_vector_type(8)));
typedef __fp16   fp16x2 __attribute__((ext_vector_type(2)));
typedef float  floatx16 __attribute__((ext_vector_type(16)));
typedef unsigned int uint_t;

union HU { half2v h; uint_t u; };
union HU2 { fp16x2 h; uint_t u; };

__device__ __forceinline__ uint_t pk2(float a, float b) {
    HU2 x; x.h = __builtin_amdgcn_cvt_pkrtz(a, b);   // v_cvt_pkrtz_f16_f32
    return x.u;
}

// ---------------------------------------------------------------------------
// Kernel 1: prep. UNCHANGED from R9/R10 (frozen).
// ---------------------------------------------------------------------------
__global__ __launch_bounds__(256) void k_prep(
    const float* __restrict__ xyz,
    const float* __restrict__ features,
    const float* __restrict__ W_gv,
    const float* __restrict__ W_gu,
    const float* __restrict__ s_gu, const float* __restrict__ b_gu,
    const float* __restrict__ s_gv, const float* __restrict__ b_gv,
    const float* __restrict__ W_h,  const float* __restrict__ s_h,
    float* __restrict__ out_xyz,
    _Float16* __restrict__ Bpack,
    uint_t* __restrict__ QsH,
    uint_t* __restrict__ PcatH)
{
    const int blk = blockIdx.x;
    const int b   = blk >> 8;
    const int n0  = (blk & 255) * 16;
    const int t   = threadIdx.x;

    if (t < 48) { int e = blk*48 + t; out_xyz[e] = xyz[e]; }
    if (t >= 64 && t < 80) {
        int e = blk*16 + (t - 64);
        int j = e & 7, l = (e >> 3) & 63, c = (e >> 9) & 7, ob = e >> 12;
        int o = ob*32 + (l & 31);
        int i = c*16 + (l >> 5)*8 + j;
        Bpack[e] = (_Float16)(W_h[o*DH_ + i] * s_h[o]);
    }

    __shared__ __align__(16) float ftile[64 * 17];   // [c][n], stride 17
    __shared__ __align__(16) float wtile[64 * 68];   // [c][o], stride 68

    {
        const int c = t >> 2, nq = t & 3;
        const float4 f4 = *(const float4*)&features[(b*C_ + c)*N_ + n0 + nq*4];
        ftile[c*17 + nq*4 + 0] = f4.x;
        ftile[c*17 + nq*4 + 1] = f4.y;
        ftile[c*17 + nq*4 + 2] = f4.z;
        ftile[c*17 + nq*4 + 3] = f4.w;
    }
#pragma unroll
    for (int r = 0; r < 4; r++) {
        const int e4 = r*256 + t, o = e4 >> 4, c0 = (e4 & 15)*4;
        const float4 w4 = *(const float4*)&W_gv[o*C_ + c0];
        wtile[(c0+0)*68 + o] = w4.x;
        wtile[(c0+1)*68 + o] = w4.y;
        wtile[(c0+2)*68 + o] = w4.z;
        wtile[(c0+3)*68 + o] = w4.w;
    }
    __syncthreads();

    const int n  = t >> 4;
    const int oq = t & 15;
    const int o0 = oq * 4;

    float acc[4] = {};
#pragma unroll 4
    for (int c = 0; c < 64; c++) {
        const float a = ftile[c*17 + n];
        const float4 wv = *(const float4*)&wtile[c*68 + o0];
        acc[0] = fmaf(a, wv.x, acc[0]);
        acc[1] = fmaf(a, wv.y, acc[1]);
        acc[2] = fmaf(a, wv.z, acc[2]);
        acc[3] = fmaf(a, wv.w, acc[3]);
    }

    const int bn = b*N_ + n0 + n;
    const float x0 = xyz[bn*3+0], x1 = xyz[bn*3+1], x2 = xyz[bn*3+2];

    const float4 sgu = *(const float4*)&s_gu[o0];
    const float4 bgu = *(const float4*)&b_gu[o0];
    const float4 sgv = *(const float4*)&s_gv[o0];
    const float4 bgv = *(const float4*)&b_gv[o0];

    float q[4], r[4];
#pragma unroll
    for (int jj = 0; jj < 4; jj++) {
        const int o = o0 + jj;
        q[jj] = x0*W_gu[o*6+0] + x1*W_gu[o*6+1] + x2*W_gu[o*6+2];
        r[jj] = x0*W_gu[o*6+3] + x1*W_gu[o*6+4] + x2*W_gu[o*6+5];
    }
    uint2 qa, pa;
    qa.x = pk2(q[0]*sgu.x+bgu.x, q[1]*sgu.y+bgu.y);
    qa.y = pk2(q[2]*sgu.z+bgu.z, q[3]*sgu.w+bgu.w);
    pa.x = pk2(r[0]*sgu.x, r[1]*sgu.y);
    pa.y = pk2(r[2]*sgu.z, r[3]*sgu.w);
    *(uint2*)&QsH  [bn*64 + oq*2] = qa;
    *(uint2*)&PcatH[bn*64 + oq*2] = pa;
    qa.x = pk2(acc[0]*sgv.x+bgv.x, acc[1]*sgv.y+bgv.y);
    qa.y = pk2(acc[2]*sgv.z+bgv.z, acc[3]*sgv.w+bgv.w);
    pa.x = pk2(acc[0]*sgv.x, acc[1]*sgv.y);
    pa.y = pk2(acc[2]*sgv.z, acc[3]*sgv.w);
    *(uint2*)&QsH  [bn*64 + 32 + oq*2] = qa;
    *(uint2*)&PcatH[bn*64 + 32 + oq*2] = pa;
}

// ---------------------------------------------------------------------------
// Kernel 2: wave-private main. 64-thr blocks (1 wave), PPW=4, grid 4096.
//  No __syncthreads anywhere: fuse + pooled are private to the single wave
//  (per-wave DS in-order execution guarantees WAR safety on the single
//  fuse buffer). All 4 W_h B-fragment sets resident (128 VGPR). Per point:
//  32 scalar-addressed row-gathers issued one MFMA-phase ahead; fuse built
//  with pk f16 ops; 16 ds_read_b64 feed 32 MFMAs; pool via
//  max(x+b,0) = max(x,-b)+b identity (2 ops/elem) + one +32b after fold.
//  f-layer + residual fused, W_f in registers.
// ---------------------------------------------------------------------------
__global__ __launch_bounds__(64, 2) void k_main(
    const int*      __restrict__ idx,
    const uint_t*   __restrict__ QsH,
    const uint_t*   __restrict__ PcatH,
    const _Float16* __restrict__ Bpack,
    const float*    __restrict__ b_h,
    const float*    __restrict__ W_f,
    const float*    __restrict__ s_f, const float* __restrict__ b_f,
    const float*    __restrict__ features,
    float* __restrict__ outF)
{
    const int lane = threadIdx.x;
    const int m    = lane & 31;
    const int hh   = lane >> 5;

    __shared__ uint_t fuse[32 * 66];                 // single buffer, wave-private
    __shared__ __align__(16) float pooled[PPW * 132];

    half8 Bf[4][8];
#pragma unroll
    for (int ob = 0; ob < 4; ob++)
#pragma unroll
        for (int c = 0; c < 8; c++)
            Bf[ob][c] = *(const half8*)&Bpack[((ob*8 + c)*64 + lane)*8];

    float nbh[4], b32[4];
#pragma unroll
    for (int ob = 0; ob < 4; ob++) {
        const float bh = b_h[ob*32 + m];
        nbh[ob] = -bh;
        b32[ob] = 32.f * bh;
    }

    const int bnb   = blockIdx.x * PPW;
    const int base0 = bnb & ~(N_ - 1);               // b*N_
    const half2v zero2 = {(_Float16)0.f, (_Float16)0.f};
    (void)zero2;

    uint_t pg[32];
    uint_t qw;

    // prologue: scalar idx row p0, 32 coalesced row-gathers, build fuse
    {
        const int n0p = bnb & (N_ - 1);
        const int* ip = idx + n0p*K_;                // uniform -> s_load
        int js[32];
#pragma unroll
        for (int it = 0; it < 32; it++) js[it] = ip[it];
        qw = QsH[(size_t)bnb*64 + lane];
#pragma unroll
        for (int it = 0; it < 32; it++)
            pg[it] = PcatH[((size_t)(base0 + js[it]) << 6) + lane];
#pragma unroll
        for (int it = 0; it < 32; it++) {
            HU a, pv; a.u = qw; pv.u = pg[it];
            half2v v = a.h + pv.h;                   // v_pk_add_f16
            HU o2; o2.h = __builtin_elementwise_max(v, (half2v){(_Float16)0.f,(_Float16)0.f});
            fuse[it*66 + lane] = o2.u;
        }
    }

#pragma unroll
    for (int p = 0; p < PPW; p++) {
        // ---- A: prefetch point p+1 (scalar idx + 32 gathers into pg) ----
        uint_t qw_n = 0;
        if (p + 1 < PPW) {
            const int np = (bnb + p + 1) & (N_ - 1);
            const int* ip = idx + np*K_;             // uniform -> s_load
            int js[32];
#pragma unroll
            for (int it = 0; it < 32; it++) js[it] = ip[it];
            qw_n = QsH[(size_t)(bnb + p + 1)*64 + lane];
#pragma unroll
            for (int it = 0; it < 32; it++)
                pg[it] = PcatH[((size_t)(base0 + js[it]) << 6) + lane];
        }

        // ---- B: 16 A-reads feed 32 MFMAs (4 o-sets) ----
        floatx16 acc0 = {}, acc1 = {}, acc2 = {}, acc3 = {};
#pragma unroll
        for (int c = 0; c < 8; c++) {
            const int wb = m*66 + c*8 + hh*4;
            union { uint_t u[4]; half8 h; } av;
            *(uint2*)&av.u[0] = *(const uint2*)&fuse[wb];
            *(uint2*)&av.u[2] = *(const uint2*)&fuse[wb + 2];
            acc0 = __builtin_amdgcn_mfma_f32_32x32x16_f16(av.h, Bf[0][c], acc0, 0, 0, 0);
            acc1 = __builtin_amdgcn_mfma_f32_32x32x16_f16(av.h, Bf[1][c], acc1, 0, 0, 0);
            acc2 = __builtin_amdgcn_mfma_f32_32x32x16_f16(av.h, Bf[2][c], acc2, 0, 0, 0);
            acc3 = __builtin_amdgcn_mfma_f32_32x32x16_f16(av.h, Bf[3][c], acc3, 0, 0, 0);
        }

        // ---- pool: sum_r max(x, -b) per set, fold halves, +32b once ----
        float v0 = 0.f, v1 = 0.f, v2 = 0.f, v3 = 0.f;
#pragma unroll
        for (int rg = 0; rg < 16; rg++) {
            v0 += fmaxf(acc0[rg], nbh[0]);
            v1 += fmaxf(acc1[rg], nbh[1]);
            v2 += fmaxf(acc2[rg], nbh[2]);
            v3 += fmaxf(acc3[rg], nbh[3]);
        }
        v0 += __shfl_xor(v0, 32);
        v1 += __shfl_xor(v1, 32);
        v2 += __shfl_xor(v2, 32);
        v3 += __shfl_xor(v3, 32);
        if (hh == 0) {
            pooled[p*132 +  0 + m] = v0 + b32[0];
            pooled[p*132 + 32 + m] = v1 + b32[1];
            pooled[p*132 + 64 + m] = v2 + b32[2];
            pooled[p*132 + 96 + m] = v3 + b32[3];
        }

        // ---- C: build fuse for p+1 (in-order DS => safe after B's reads) ----
        if (p + 1 < PPW) {
#pragma unroll
            for (int it = 0; it < 32; it++) {
                HU a, pv; a.u = qw_n; pv.u = pg[it];
                half2v v = a.h + pv.h;
                HU o2; o2.h = __builtin_elementwise_max(v, (half2v){(_Float16)0.f,(_Float16)0.f});
                fuse[it*66 + lane] = o2.u;
            }
        }
    }

    // ---- f layer + residual (lane = c, 4 points as float4 columns) ----
    const int b  = bnb >> 12;
    const int n0 = bnb & (N_ - 1);
    const int c  = lane;

    float wreg[DH_ / 4][4];   // W_f row in registers via float4 loads
    float accf[PPW] = {};
#pragma unroll 8
    for (int i0 = 0; i0 < DH_; i0 += 4) {
        const float4 wv = *(const float4*)&W_f[c*DH_ + i0];
        (void)wreg;
#pragma unroll
        for (int r = 0; r < PPW; r++) {
            const float4 p4 = *(const float4*)&pooled[r*132 + i0];
            accf[r] += wv.x*p4.x + wv.y*p4.y + wv.z*p4.z + wv.w*p4.w;
        }
    }
    const float sfc = s_f[c] * (1.f/(float)K_);
    const float bfc = b_f[c];
    const float4 fr = *(const float4*)&features[(b*C_ + c)*N_ + n0];
    float4 ov;
    ov.x = fmaxf(accf[0]*sfc + bfc, 0.f) + fr.x;
    ov.y = fmaxf(accf[1]*sfc + bfc, 0.f) + fr.y;
    ov.z = fmaxf(accf[2]*sfc + bfc, 0.f) + fr.z;
    ov.w = fmaxf(accf[3]*sfc + bfc, 0.f) + fr.w;
    *(float4*)&outF[(b*C_ + c)*N_ + n0] = ov;
}

// ---------------------------------------------------------------------------
extern "C" void kernel_launch(void* const* d_in, const int* in_sizes, int n_in,
                              void* d_out, int out_size, void* d_ws, size_t ws_size,
                              hipStream_t stream)
{
    const float* xyz      = (const float*)d_in[0];
    const float* features = (const float*)d_in[1];
    const int*   idx      = (const int*)  d_in[2];
    const float* W_gu     = (const float*)d_in[3];
    const float* s_gu     = (const float*)d_in[4];
    const float* b_gu     = (const float*)d_in[5];
    const float* W_gv     = (const float*)d_in[6];
    const float* s_gv     = (const float*)d_in[7];
    const float* b_gv     = (const float*)d_in[8];
    const float* W_h      = (const float*)d_in[9];
    const float* s_h      = (const float*)d_in[10];
    const float* b_h      = (const float*)d_in[11];
    const float* W_f      = (const float*)d_in[12];
    const float* s_f      = (const float*)d_in[13];
    const float* b_f      = (const float*)d_in[14];

    float* out  = (float*)d_out;          // tuple: xyz first, then out
    float* outF = out + B_*N_*3;

    // workspace carve (~8.1 MB)
    char* wp = (char*)d_ws;
    uint_t*   QsH   = (uint_t*)wp;   wp += (size_t)B_*N_*64*4;    // 4 MB
    uint_t*   PcatH = (uint_t*)wp;   wp += (size_t)B_*N_*64*4;    // 4 MB
    _Float16* Bpack = (_Float16*)wp; wp += DH_*DH_*2;             // 32 KB

    k_prep<<<B_*(N_/16), 256, 0, stream>>>(xyz, features, W_gv, W_gu,
                                           s_gu, b_gu, s_gv, b_gv, W_h, s_h,
                                           out, Bpack, QsH, PcatH);
    k_main<<<(B_*N_)/PPW, 64, 0, stream>>>(idx, QsH, PcatH, Bpack, b_h,
                                           W_f, s_f, b_f, features, outF);
}